// Round 2
// baseline (2199.546 us; speedup 1.0000x reference)
//
#include <hip/hip_runtime.h>

// Submanifold sparse conv block, fixed problem size:
// n = 400000 voxels, C = 64, spatial dims B=2, T=21, H=400, W=400.
// lin[i] = ((b*21+t)*400+y)*400+x, sorted ascending by construction.
//
// Round-2 structure: block = 256 thr / 4 waves, 128 voxels per block
// (32 per wave, lane = cout). Per offset k: W^T[k] staged in LDS
// (double-buffered, padded row stride 68 floats = 272 B -> conflict-free
// ds_read_b128), each lane keeps its weight column in 64 VGPRs and
// reuses it across 32 voxels. Neighbor table built once per block in LDS
// from the dense grid map (all lookups issued batched -> latency hidden).

#define SBB_T 21
#define SBB_H 400
#define SBB_W 400
#define SBB_TOTAL (2 * SBB_T * SBB_H * SBB_W)   /* 6,720,000 grid sites */
#define SBB_N 400000

#define WT_STRIDE 68                 /* padded W^T row, fp32 dwords */
#define WT_TILE (64 * WT_STRIDE)     /* 4352 dwords = 17408 B per offset */
#define VPB 128                      /* voxels per block */
#define VPW 32                       /* voxels per wave */

__global__ void sbb_lin_kernel(const int* idxs, int* lin, int n) {
    int i = blockIdx.x * 256 + threadIdx.x;
    if (i < n) {
        int b = idxs[4 * i];
        int t = idxs[4 * i + 1];
        int y = idxs[4 * i + 2];
        int x = idxs[4 * i + 3];
        lin[i] = ((b * 21 + t) * 400 + y) * 400 + x;
    }
}

__global__ void sbb_map_init(int* map) {
    int i = blockIdx.x * 256 + threadIdx.x;
    if (i < SBB_TOTAL) map[i] = -1;
}

__global__ void sbb_map_set(const int* lin, int* map, int n) {
    int i = blockIdx.x * 256 + threadIdx.x;
    if (i < n) map[lin[i]] = i;
}

// Transpose + pad weights: wt[k][co*68 + ci] = w[k][ci][co].
__global__ void sbb_wt_kernel(const float* __restrict__ w, float* __restrict__ wt) {
    int k = blockIdx.x;
    const float* ws = w + (size_t)k * 4096;
    float* wd = wt + (size_t)k * WT_TILE;
    for (int e = threadIdx.x; e < 4096; e += 256) {
        int ci = e >> 6;
        int co = e & 63;
        wd[co * WT_STRIDE + ci] = ws[e];
    }
}

// Diagnostic: fill fp32 output with a constant.
__global__ void sbb_fill_kernel(float* p, int nel, float val) {
    int i = blockIdx.x * 256 + threadIdx.x;
    if (i < nel) p[i] = val;
}

template<int IN_BF16, int OUT_BF16, int USE_RES>
__global__ __launch_bounds__(256, 3)
void sbb_conv(
    const float* __restrict__ featsf,          // [n][64] fp32   (iff !IN_BF16)
    const unsigned short* __restrict__ featsb, // [n][64] bf16   (iff IN_BF16)
    const float* __restrict__ wt,              // [27][WT_TILE] padded W^T
    const float* __restrict__ gamma,
    const float* __restrict__ beta,
    const float* __restrict__ residual,        // [n][64] fp32 (iff USE_RES)
    float* __restrict__ outf,                  // iff !OUT_BF16
    unsigned short* __restrict__ outb,         // iff OUT_BF16
    const int* __restrict__ lin,
    const int* __restrict__ idxs,
    const int* __restrict__ map,
    int n)
{
    __shared__ int s_lin[VPB];
    __shared__ int s_tyx[VPB];
    __shared__ int s_nbr[27 * VPB];                 // [k][v]
    __shared__ __align__(16) float s_w[2][WT_TILE]; // double-buffered W^T

    int tid = threadIdx.x;
    int vox0 = blockIdx.x * VPB;

    // ---- phase 00: voxel meta into LDS ----
    if (tid < VPB) {
        int v = vox0 + tid;
        if (v < n) {
            const int4 q = *(const int4*)(idxs + 4 * (size_t)v);
            s_tyx[tid] = (q.y << 20) | (q.z << 10) | q.w;  // t,y,x packed
            s_lin[tid] = lin[v];
        } else {
            s_tyx[tid] = 0;
            s_lin[tid] = -1;
        }
    }
    __syncthreads();

    // ---- phase 0: neighbor table (batched independent map lookups) ----
    #pragma unroll 4
    for (int j = tid; j < 27 * VPB; j += 256) {
        int k = j >> 7;              // VPB == 128
        int v = j & (VPB - 1);
        int dt = k / 9 - 1;
        int rem = k % 9;
        int dy = rem / 3 - 1;
        int dx = rem % 3 - 1;
        int tyx = s_tyx[v];
        int t0 = tyx >> 20, y0 = (tyx >> 10) & 1023, x0 = tyx & 1023;
        int ml = s_lin[v];
        int tt = t0 + dt, yy = y0 + dy, xx = x0 + dx;
        bool valid = (ml >= 0) & ((unsigned)tt < 21u) & ((unsigned)yy < 400u)
                   & ((unsigned)xx < 400u);
        int key = ml + dt * (SBB_H * SBB_W) + dy * SBB_W + dx;
        int ck = valid ? key : 0;    // clamped -> branch-free pipelined load
        int lo = map[ck];
        s_nbr[j] = valid ? lo : -1;
    }

    // ---- stage k=0 into buf 0 (reg -> LDS; visible after first barrier) ----
    {
        const float* src = wt;
        #pragma unroll
        for (int c = 0; c < 4; ++c) {
            int idx = tid + c * 256;
            uint4 d = *(const uint4*)(src + (size_t)idx * 4);
            *(uint4*)&s_w[0][idx * 4] = d;
        }
        if (tid < 64) {
            int idx = tid + 1024;
            uint4 d = *(const uint4*)(src + (size_t)idx * 4);
            *(uint4*)&s_w[0][idx * 4] = d;
        }
    }

    int wid = tid >> 6;
    int co = tid & 63;
    int vbase = wid * VPW;

    float acc[VPW];
    #pragma unroll
    for (int v = 0; v < VPW; ++v) acc[v] = 0.0f;

    for (int k = 0; k < 27; ++k) {
        __syncthreads();   // stage k visible; everyone done with buf k-1
        int cur = k & 1;

        // issue next-tile global loads early (write to LDS after compute)
        uint4 r0, r1, r2, r3, r4;
        if (k < 26) {
            const float* src = wt + (size_t)(k + 1) * WT_TILE;
            r0 = *(const uint4*)(src + (size_t)(tid + 0) * 4);
            r1 = *(const uint4*)(src + (size_t)(tid + 256) * 4);
            r2 = *(const uint4*)(src + (size_t)(tid + 512) * 4);
            r3 = *(const uint4*)(src + (size_t)(tid + 768) * 4);
            if (tid < 64) r4 = *(const uint4*)(src + (size_t)(tid + 1024) * 4);
        }

        // this lane's W^T row -> 64 VGPRs (conflict-free b128: 272 B stride)
        float4 w4[16];
        #pragma unroll
        for (int j = 0; j < 16; ++j)
            w4[j] = *(const float4*)&s_w[cur][co * WT_STRIDE + j * 4];

        const int* nb = &s_nbr[(k << 7) + vbase];
        #pragma unroll
        for (int v4 = 0; v4 < VPW / 4; ++v4) {
            int4 nq = *(const int4*)(nb + v4 * 4);
            #pragma unroll
            for (int u = 0; u < 4; ++u) {
                int lo = (u == 0) ? nq.x : (u == 1) ? nq.y : (u == 2) ? nq.z : nq.w;
                if (lo < 0) continue;     // wave-uniform branch
                const int vv = v4 * 4 + u;
                if (IN_BF16) {
                    const uint4* fb = (const uint4*)(featsb + (size_t)lo * 64);
                    #pragma unroll
                    for (int j2 = 0; j2 < 8; ++j2) {
                        uint4 uu = fb[j2];
                        float4 wa = w4[2 * j2], wb = w4[2 * j2 + 1];
                        acc[vv] += __uint_as_float(uu.x << 16) * wa.x;
                        acc[vv] += __uint_as_float(uu.x & 0xffff0000u) * wa.y;
                        acc[vv] += __uint_as_float(uu.y << 16) * wa.z;
                        acc[vv] += __uint_as_float(uu.y & 0xffff0000u) * wa.w;
                        acc[vv] += __uint_as_float(uu.z << 16) * wb.x;
                        acc[vv] += __uint_as_float(uu.z & 0xffff0000u) * wb.y;
                        acc[vv] += __uint_as_float(uu.w << 16) * wb.z;
                        acc[vv] += __uint_as_float(uu.w & 0xffff0000u) * wb.w;
                    }
                } else {
                    const float4* fr = (const float4*)(featsf + (size_t)lo * 64);
                    #pragma unroll
                    for (int j = 0; j < 16; ++j) {
                        float4 f = fr[j];
                        float4 ww = w4[j];
                        acc[vv] += f.x * ww.x;
                        acc[vv] += f.y * ww.y;
                        acc[vv] += f.z * ww.z;
                        acc[vv] += f.w * ww.w;
                    }
                }
            }
        }

        // write next tile into the other buffer
        if (k < 26) {
            int nxt = cur ^ 1;
            *(uint4*)&s_w[nxt][(tid + 0) * 4] = r0;
            *(uint4*)&s_w[nxt][(tid + 256) * 4] = r1;
            *(uint4*)&s_w[nxt][(tid + 512) * 4] = r2;
            *(uint4*)&s_w[nxt][(tid + 768) * 4] = r3;
            if (tid < 64) *(uint4*)&s_w[nxt][(tid + 1024) * 4] = r4;
        }
    }

    // ---- epilogue: LayerNorm per voxel (64-lane butterfly), store ----
    float g = gamma[co], b = beta[co];
    #pragma unroll
    for (int v = 0; v < VPW; ++v) {
        int vx = vox0 + vbase + v;
        float a = acc[v];
        float s = a, q = a * a;
        #pragma unroll
        for (int m = 32; m > 0; m >>= 1) {
            s += __shfl_xor(s, m, 64);
            q += __shfl_xor(q, m, 64);
        }
        float mean = s * 0.015625f;
        float var = q * 0.015625f - mean * mean;
        var = var < 0.0f ? 0.0f : var;
        float rstd = rsqrtf(var + 1e-5f);
        float yv = (a - mean) * rstd * g + b;
        if (vx < n) {
            size_t oi = (size_t)vx * 64 + co;
            if (USE_RES) yv += residual[oi];
            if (yv < 0.0f) yv = 0.0f;
            if (OUT_BF16) {
                unsigned uu = __float_as_uint(yv);
                unsigned rr = uu + 0x7fffu + ((uu >> 16) & 1u);
                outb[oi] = (unsigned short)(rr >> 16);
            } else {
                outf[oi] = yv;
            }
        }
    }
}

// ---- round-1 kernel kept verbatim as the proven fallback ----
__global__ void sbb_conv_old(
    const float* featsf, const unsigned short* featsb, const float* w,
    const float* gamma, const float* beta, const float* residual,
    float* outf, unsigned short* outb, const int* lin, const int* idxs,
    const int* map, int n, int use_residual, int feats_bf16, int out_bf16,
    int use_map)
{
    int tid = threadIdx.x;
    int vox = blockIdx.x * 4 + (tid >> 6);
    if (vox >= n) return;
    int co = tid & 63;

    int t0 = idxs[4 * vox + 1];
    int y0 = idxs[4 * vox + 2];
    int x0 = idxs[4 * vox + 3];
    int mylin = lin[vox];

    float acc = 0.0f;
    #pragma unroll
    for (int dt = -1; dt <= 1; ++dt) {
        int tt = t0 + dt;
        if (tt < 0 || tt >= SBB_T) continue;
        #pragma unroll
        for (int dy = -1; dy <= 1; ++dy) {
            int yy = y0 + dy;
            if (yy < 0 || yy >= SBB_H) continue;
            #pragma unroll
            for (int dx = -1; dx <= 1; ++dx) {
                int xx = x0 + dx;
                if (xx < 0 || xx >= SBB_W) continue;
                int key = mylin + dt * (SBB_H * SBB_W) + dy * SBB_W + dx;
                int lo;
                if (use_map) {
                    lo = map[key];
                } else {
                    int l = 0, h = n;
                    while (l < h) {
                        int m = (l + h) >> 1;
                        if (lin[m] < key) l = m + 1; else h = m;
                    }
                    lo = (l < n && lin[l] == key) ? l : -1;
                }
                if (lo < 0) continue;
                int kk = (dt + 1) * 9 + (dy + 1) * 3 + (dx + 1);
                const float* wr = w + kk * 4096 + co;
                if (feats_bf16) {
                    const unsigned short* fr = featsb + (size_t)lo * 64;
                    #pragma unroll 4
                    for (int c4 = 0; c4 < 16; ++c4) {
                        ushort4 fv = *(const ushort4*)(fr + c4 * 4);
                        const float* wp = wr + c4 * 256;
                        acc += __uint_as_float(((unsigned)fv.x) << 16) * wp[0];
                        acc += __uint_as_float(((unsigned)fv.y) << 16) * wp[64];
                        acc += __uint_as_float(((unsigned)fv.z) << 16) * wp[128];
                        acc += __uint_as_float(((unsigned)fv.w) << 16) * wp[192];
                    }
                } else {
                    const float4* fr = (const float4*)(featsf + (size_t)lo * 64);
                    #pragma unroll 4
                    for (int c4 = 0; c4 < 16; ++c4) {
                        float4 fv = fr[c4];
                        const float* wp = wr + c4 * 256;
                        acc += fv.x * wp[0];
                        acc += fv.y * wp[64];
                        acc += fv.z * wp[128];
                        acc += fv.w * wp[192];
                    }
                }
            }
        }
    }

    float s = acc, q = acc * acc;
    #pragma unroll
    for (int m = 32; m > 0; m >>= 1) {
        s += __shfl_xor(s, m, 64);
        q += __shfl_xor(q, m, 64);
    }
    float mean = s * 0.015625f;
    float var = q * 0.015625f - mean * mean;
    if (var < 0.0f) var = 0.0f;
    float rstd = rsqrtf(var + 1e-5f);

    float yv = (acc - mean) * rstd * gamma[co] + beta[co];
    int oi = vox * 64 + co;
    if (use_residual) yv += residual[oi];
    if (yv < 0.0f) yv = 0.0f;
    if (out_bf16) {
        unsigned u = __float_as_uint(yv);
        unsigned r = u + 0x7fffu + ((u >> 16) & 1u);
        outb[oi] = (unsigned short)(r >> 16);
    } else {
        outf[oi] = yv;
    }
}

extern "C" void kernel_launch(void* const* d_in, const int* in_sizes, int n_in,
                              void* d_out, int out_size, void* d_ws, size_t ws_size,
                              hipStream_t stream) {
    const float* feats = (const float*)d_in[0];
    const int* idxs = (const int*)d_in[1];
    const float* w1 = (const float*)d_in[2];
    const float* g1 = (const float*)d_in[3];
    const float* b1 = (const float*)d_in[4];
    const float* w2 = (const float*)d_in[5];
    const float* g2 = (const float*)d_in[6];
    const float* b2 = (const float*)d_in[7];
    float* out = (float*)d_out;

    int n = SBB_N;

    size_t lin_b = (size_t)n * 4;                    // 1.6 MB
    size_t map_b = (size_t)SBB_TOTAL * 4;            // 26.88 MB
    size_t wt_b  = (size_t)27 * WT_TILE * 4;         // 470 KB per conv
    size_t midf_b = (size_t)n * 64 * 4;              // 102.4 MB fp32 mid
    size_t midb_b = (size_t)n * 64 * 2;              // 51.2 MB bf16 mid

    size_t need_T2  = lin_b + map_b + 2 * wt_b + midf_b;  // ~131.8 MB
    size_t need_T1  = lin_b + map_b + 2 * wt_b + midb_b;  // ~80.6 MB
    size_t need_old = lin_b + map_b + midb_b;             // 79.7 MB (proven)
    size_t need_min = lin_b + midb_b;                     // 52.8 MB (proven)

    if (ws_size < need_min) {
        sbb_fill_kernel<<<(n * 64 + 255) / 256, 256, 0, stream>>>(out, n * 64, 1000.0f);
        return;
    }

    int* lin = (int*)d_ws;
    int grid_lin = (n + 255) / 256;

    if (ws_size >= need_T1) {
        // new structured path
        int* map = (int*)((char*)d_ws + lin_b);
        float* wt1 = (float*)((char*)d_ws + lin_b + map_b);
        float* wt2 = wt1 + (size_t)27 * WT_TILE;
        char* midp = (char*)d_ws + lin_b + map_b + 2 * wt_b;
        int mid_f32 = (ws_size >= need_T2) ? 1 : 0;

        sbb_lin_kernel<<<grid_lin, 256, 0, stream>>>(idxs, lin, n);
        sbb_map_init<<<(SBB_TOTAL + 255) / 256, 256, 0, stream>>>(map);
        sbb_map_set<<<grid_lin, 256, 0, stream>>>(lin, map, n);
        sbb_wt_kernel<<<27, 256, 0, stream>>>(w1, wt1);
        sbb_wt_kernel<<<27, 256, 0, stream>>>(w2, wt2);

        int grid_conv = (n + VPB - 1) / VPB;   // 3125
        if (mid_f32) {
            float* mid = (float*)midp;
            sbb_conv<0, 0, 0><<<grid_conv, 256, 0, stream>>>(
                feats, (const unsigned short*)feats, wt1, g1, b1, feats,
                mid, (unsigned short*)mid, lin, idxs, map, n);
            sbb_conv<0, 0, 1><<<grid_conv, 256, 0, stream>>>(
                mid, (const unsigned short*)mid, wt2, g2, b2, feats,
                out, (unsigned short*)out, lin, idxs, map, n);
        } else {
            unsigned short* mid = (unsigned short*)midp;
            sbb_conv<0, 1, 0><<<grid_conv, 256, 0, stream>>>(
                feats, (const unsigned short*)feats, wt1, g1, b1, feats,
                (float*)mid, mid, lin, idxs, map, n);
            sbb_conv<1, 0, 1><<<grid_conv, 256, 0, stream>>>(
                feats, mid, wt2, g2, b2, feats,
                out, (unsigned short*)out, lin, idxs, map, n);
        }
        return;
    }

    // fallback: proven round-1 path
    int use_map = (ws_size >= need_old) ? 1 : 0;
    int* map = nullptr;
    unsigned short* mid;
    if (use_map) {
        map = (int*)((char*)d_ws + lin_b);
        mid = (unsigned short*)((char*)d_ws + lin_b + map_b);
    } else {
        mid = (unsigned short*)((char*)d_ws + lin_b);
    }

    sbb_lin_kernel<<<grid_lin, 256, 0, stream>>>(idxs, lin, n);
    if (use_map) {
        sbb_map_init<<<(SBB_TOTAL + 255) / 256, 256, 0, stream>>>(map);
        sbb_map_set<<<grid_lin, 256, 0, stream>>>(lin, map, n);
    }

    sbb_conv_old<<<n / 4, 256, 0, stream>>>(
        feats, (const unsigned short*)feats, w1, g1, b1, feats,
        (float*)mid, mid, lin, idxs, map, n, 0, 0, 1, use_map);
    sbb_conv_old<<<n / 4, 256, 0, stream>>>(
        feats, mid, w2, g2, b2, feats,
        out, (unsigned short*)out, lin, idxs, map, n, 1, 1, 0, use_map);
}